// Round 7
// baseline (404.085 us; speedup 1.0000x reference)
//
#include <hip/hip_runtime.h>
#include <cstdint>
#include <cstddef>

// GlobalAttention (Luong 'general'): q = src@W^T ; x = q@MB^T ; softmax(mask) ; c = P@MB
// Outputs: d_out = [ c (8*1024*256) | align_vectors (8*1024*4096) ] fp32.
// Pipeline: k_qproj -> k_fstats -> k_stats -> k_pv4 (recompute x, p once, PV) -> k_csum
//
// R7 (pv-v4): R5/R6 pv collapses were (a) strided scalar global V-loads, (b) double
// staging of mbank, (c) 128B-row LDS aliasing mis-audited. v4: mbank read once per
// step into registers; each float4 feeds Bs [s][d] (QK, proven path) AND VT2
// (transpose via 4x ds_write_b16, key ((d>>5)^(d>>1))&7 spread on write AND read);
// Ps 80B rows; 4 blocks/CU; 2 barriers/step; nontemporal p/pc stores keep the
// XCD-pinned (b=bid&7) mbank slab L2-resident.

typedef _Float16 f16;
typedef _Float16 half8 __attribute__((ext_vector_type(8)));
typedef _Float16 half4v __attribute__((ext_vector_type(4)));
typedef float f32x4 __attribute__((ext_vector_type(4)));

#define MFMA16(a, b, c) __builtin_amdgcn_mfma_f32_16x16x32_f16((a), (b), (c), 0, 0, 0)

static constexpr int NBATCH = 8;
static constexpr int NT = 1024;   // TGT
static constexpr int NS = 4096;   // SRC
static constexpr int ND = 256;    // SDIM == TDIM
static constexpr float NEGBIG = -3.0e38f;

__device__ __forceinline__ int swz(int row, int byteInRow) {
  return byteInRow ^ ((row & 7) << 4);
}

// ---------------- K1: q16 = source @ W^T (fp16 out) ----------------
__global__ __launch_bounds__(256) void k_qproj(const float* __restrict__ src,
                                               const float* __restrict__ W,
                                               f16* __restrict__ q16) {
  __shared__ __align__(16) f16 As[64 * 64];
  __shared__ __align__(16) f16 Bs[256 * 64];
  const int tid = threadIdx.x;
  const int w = tid >> 6, l = tid & 63;
  const int wt = w >> 1, wn = w & 1;
  const int q = l >> 4, lc = l & 15;
  const int t0 = blockIdx.x * 64;

  f32x4 acc[2][8];
#pragma unroll
  for (int i = 0; i < 2; ++i)
#pragma unroll
    for (int j = 0; j < 8; ++j) acc[i][j] = (f32x4){0.f, 0.f, 0.f, 0.f};

  for (int k0 = 0; k0 < 256; k0 += 64) {
    __syncthreads();
    {
      const int r = tid >> 2, c2 = (tid & 3) * 2;
      const float* g = src + (size_t)(t0 + r) * 256 + k0 + c2 * 8;
      float4 f0 = ((const float4*)g)[0], f1 = ((const float4*)g)[1];
      float4 f2 = ((const float4*)g)[2], f3 = ((const float4*)g)[3];
      half8 h0 = {(f16)f0.x, (f16)f0.y, (f16)f0.z, (f16)f0.w,
                  (f16)f1.x, (f16)f1.y, (f16)f1.z, (f16)f1.w};
      half8 h1 = {(f16)f2.x, (f16)f2.y, (f16)f2.z, (f16)f2.w,
                  (f16)f3.x, (f16)f3.y, (f16)f3.z, (f16)f3.w};
      *(half8*)((char*)As + r * 128 + swz(r, c2 * 16)) = h0;
      *(half8*)((char*)As + r * 128 + swz(r, c2 * 16 + 16)) = h1;
    }
    {
      const int n = tid;
      const float* g = W + (size_t)n * 256 + k0;
#pragma unroll
      for (int c = 0; c < 8; ++c) {
        float4 f0 = ((const float4*)(g + c * 8))[0];
        float4 f1 = ((const float4*)(g + c * 8))[1];
        half8 h = {(f16)f0.x, (f16)f0.y, (f16)f0.z, (f16)f0.w,
                   (f16)f1.x, (f16)f1.y, (f16)f1.z, (f16)f1.w};
        *(half8*)((char*)Bs + n * 128 + swz(n, c * 16)) = h;
      }
    }
    __syncthreads();
    half8 a[2][2], bb[8][2];
#pragma unroll
    for (int mb = 0; mb < 2; ++mb)
#pragma unroll
      for (int kf = 0; kf < 2; ++kf) {
        const int r = wt * 32 + mb * 16 + lc;
        a[mb][kf] = *(const half8*)((const char*)As + r * 128 + swz(r, kf * 64 + q * 16));
      }
#pragma unroll
    for (int nb = 0; nb < 8; ++nb)
#pragma unroll
      for (int kf = 0; kf < 2; ++kf) {
        const int r = wn * 128 + nb * 16 + lc;
        bb[nb][kf] = *(const half8*)((const char*)Bs + r * 128 + swz(r, kf * 64 + q * 16));
      }
#pragma unroll
    for (int kf = 0; kf < 2; ++kf)
#pragma unroll
      for (int mb = 0; mb < 2; ++mb)
#pragma unroll
        for (int nb = 0; nb < 8; ++nb)
          acc[mb][nb] = MFMA16(a[mb][kf], bb[nb][kf], acc[mb][nb]);
  }
#pragma unroll
  for (int mb = 0; mb < 2; ++mb)
#pragma unroll
    for (int nb = 0; nb < 8; ++nb)
#pragma unroll
      for (int j = 0; j < 4; ++j) {
        const int t = t0 + wt * 32 + mb * 16 + q * 4 + j;
        const int n = wn * 128 + nb * 16 + lc;
        q16[(size_t)t * 256 + n] = (f16)acc[mb][nb][j];
      }
}

// ---------------- K2: flash stats — x via MFMA, online (m, sumexp), NO x store ----
__global__ __launch_bounds__(256, 3) void k_fstats(const float* __restrict__ mbank,
                                                   const f16* __restrict__ q16,
                                                   const int* __restrict__ mask,
                                                   float* __restrict__ pstats) {
  __shared__ __align__(16) f16 Bs[64 * 256];
  const int tid = threadIdx.x;
  const int w = tid >> 6, l = tid & 63;
  const int q = l >> 4, lc = l & 15;
  const int bid = blockIdx.x;
  const int b = bid & 7;
  const int sc = (bid >> 3) & 7;
  const int tt = bid >> 6;
  const int t0 = tt * 128;
  const int s0 = sc * 512;

  half8 aq[2][8];
#pragma unroll
  for (int mb = 0; mb < 2; ++mb)
#pragma unroll
    for (int kf = 0; kf < 8; ++kf)
      aq[mb][kf] = *(const half8*)(q16 +
          (size_t)(b * NT + t0 + w * 32 + mb * 16 + lc) * 256 + kf * 32 + q * 8);

  float mrun[8], lrun[8];
#pragma unroll
  for (int i = 0; i < 8; ++i) { mrun[i] = NEGBIG; lrun[i] = 0.f; }

  const int br = tid >> 2;
  const int cb = (tid & 3) * 64;
  for (int st = 0; st < 8; ++st) {
    const int sb = s0 + st * 64;
    __syncthreads();
    {
      const float4* g = (const float4*)(mbank + ((size_t)b * NS + sb + br) * ND + cb);
#pragma unroll
      for (int i = 0; i < 8; ++i) {
        float4 f0 = g[2 * i], f1 = g[2 * i + 1];
        half8 h = {(f16)f0.x, (f16)f0.y, (f16)f0.z, (f16)f0.w,
                   (f16)f1.x, (f16)f1.y, (f16)f1.z, (f16)f1.w};
        *(half8*)((char*)Bs + br * 512 + swz(br, cb * 2 + i * 16)) = h;
      }
    }
    __syncthreads();
    f32x4 xacc[2][4];
#pragma unroll
    for (int i = 0; i < 2; ++i)
#pragma unroll
      for (int j = 0; j < 4; ++j) xacc[i][j] = (f32x4){0.f, 0.f, 0.f, 0.f};
#pragma unroll
    for (int kf = 0; kf < 8; ++kf)
#pragma unroll
      for (int nb = 0; nb < 4; ++nb) {
        const int rs = nb * 16 + lc;
        half8 bb = *(const half8*)((const char*)Bs + rs * 512 + swz(rs, kf * 64 + q * 16));
#pragma unroll
        for (int mb = 0; mb < 2; ++mb)
          xacc[mb][nb] = MFMA16(aq[mb][kf], bb, xacc[mb][nb]);
      }
    bool keep[4];
#pragma unroll
    for (int nb = 0; nb < 4; ++nb)
      keep[nb] = mask[(size_t)b * NS + sb + nb * 16 + lc] != 0;
#pragma unroll
    for (int mb = 0; mb < 2; ++mb)
#pragma unroll
      for (int j = 0; j < 4; ++j) {
        float v[4];
#pragma unroll
        for (int nb = 0; nb < 4; ++nb) v[nb] = keep[nb] ? xacc[mb][nb][j] : NEGBIG;
        float m2 = fmaxf(fmaxf(v[0], v[1]), fmaxf(v[2], v[3]));
#pragma unroll
        for (int d = 1; d < 16; d <<= 1) m2 = fmaxf(m2, __shfl_xor(m2, d));
        float s2 = 0.f;
#pragma unroll
        for (int nb = 0; nb < 4; ++nb) s2 += __expf(v[nb] - m2);
#pragma unroll
        for (int d = 1; d < 16; d <<= 1) s2 += __shfl_xor(s2, d);
        const int idx = mb * 4 + j;
        const float mn = fmaxf(mrun[idx], m2);
        lrun[idx] = lrun[idx] * __expf(mrun[idx] - mn) + s2 * __expf(m2 - mn);
        mrun[idx] = mn;
      }
  }
  if (lc == 0) {
#pragma unroll
    for (int mb = 0; mb < 2; ++mb)
#pragma unroll
      for (int j = 0; j < 4; ++j) {
        const int row = t0 + w * 32 + mb * 16 + q * 4 + j;
        const int idx = mb * 4 + j;
        pstats[(((size_t)b * NT + row) * 8 + sc) * 2 + 0] = mrun[idx];
        pstats[(((size_t)b * NT + row) * 8 + sc) * 2 + 1] = lrun[idx];
      }
  }
}

// ---------------- K3: reduce 8 chunk partials -> m, 1/l per row ----------------
__global__ __launch_bounds__(256) void k_stats(const float* __restrict__ pstats,
                                               float* __restrict__ sm,
                                               float* __restrict__ slinv) {
  const int r = blockIdx.x * 256 + threadIdx.x;
  const float4* p = (const float4*)(pstats + (size_t)r * 16);
  float4 v[4];
  float mm = NEGBIG;
#pragma unroll
  for (int i = 0; i < 4; ++i) {
    v[i] = p[i];
    mm = fmaxf(mm, fmaxf(v[i].x, v[i].z));
  }
  float ll = 0.f;
#pragma unroll
  for (int i = 0; i < 4; ++i)
    ll += v[i].y * __expf(v[i].x - mm) + v[i].w * __expf(v[i].z - mm);
  sm[r] = mm;
  slinv[r] = (ll > 0.f) ? (1.f / ll) : 0.f;
}

// ---------------- K4 v4: recompute x, p once -> align ; partial c = P@V ----------
// flat grid 8*kcN*16: b = bid&7 (XCD pin), kc = (bid>>3)%kcN, tt = (bid>>3)/kcN.
// block 256 = 4 waves, each owns 16 t-rows of the 64-row t-tile, full d=256.
// Per 32-s step: {reg-load 8 float4} bar {Bs[s][d] + VT2 transpose-scatter} bar
// {QK 16 MFMA, mask/p, nt-store p, Ps, PV 16 MFMA}.
__global__ __launch_bounds__(256, 4) void k_pv4(const float* __restrict__ mbank,
                                                const f16* __restrict__ q16,
                                                const int* __restrict__ mask,
                                                const float* __restrict__ sm,
                                                const float* __restrict__ slinv,
                                                float* __restrict__ alignv,
                                                f16* __restrict__ pc, int kcN) {
  __shared__ __align__(16) f16 Bs[32 * 256];       // [s][d], 512B rows, swz (16K)
  __shared__ __align__(16) f16 VT2[128 * 64];      // packed transpose (16K)
  __shared__ __align__(16) char PsB[4 * 16 * 80];  // per-wave [16t][40 f16] (5K)
  const int tid = threadIdx.x;
  const int w = tid >> 6, l = tid & 63;
  const int q = l >> 4, lc = l & 15;
  const int bid = blockIdx.x;
  const int b = bid & 7;
  const int r2 = bid >> 3;
  const int kc = r2 % kcN;
  const int tt = r2 / kcN;
  const int schunk = NS / kcN;
  const int nst = schunk >> 5;
  const int t0 = tt * 64;
  const int s0 = kc * schunk;

  // A fragments: this wave's 16 t-rows (loaded once)
  half8 aq[8];
  {
    const f16* qrow = q16 + (size_t)(b * NT + t0 + w * 16 + lc) * 256;
#pragma unroll
    for (int kf = 0; kf < 8; ++kf)
      aq[kf] = *(const half8*)(qrow + kf * 32 + q * 8);
  }
  float mrowv[4], linvv[4];
#pragma unroll
  for (int j = 0; j < 4; ++j) {
    const size_t rg = (size_t)b * NT + t0 + w * 16 + q * 4 + j;
    mrowv[j] = sm[rg];
    linvv[j] = slinv[rg];
  }

  f32x4 acc[16];
#pragma unroll
  for (int i = 0; i < 16; ++i) acc[i] = (f32x4){0.f, 0.f, 0.f, 0.f};

  // staging ownership: row r (0..31), 32 f32 cols starting at c0
  const int r = tid >> 3;
  const int c0 = (tid & 7) * 32;
  const float* gsrc = mbank + ((size_t)b * NS + s0 + r) * ND + c0;

  // prologue: preload batch1 of step 0
  float4 b1[4];
#pragma unroll
  for (int i = 0; i < 4; ++i) b1[i] = ((const float4*)gsrc)[i];

  for (int st = 0; st < nst; ++st) {
    const int sb = s0 + st * 32;
    const float4* gstep = (const float4*)(gsrc + (size_t)st * 32 * ND);

    __syncthreads();  // all waves done with prev step's LDS
    // issue batch2 loads (fly during batch1 LDS writes)
    float4 b2[4];
#pragma unroll
    for (int i = 0; i < 4; ++i) b2[i] = gstep[4 + i];
    // write batch1: Bs half4v + VT2 4x b16 scatter
#pragma unroll
    for (int i = 0; i < 4; ++i) {
      const int c = c0 + i * 4;
      half4v hv = {(f16)b1[i].x, (f16)b1[i].y, (f16)b1[i].z, (f16)b1[i].w};
      *(half4v*)((char*)Bs + r * 512 + ((2 * c) ^ ((r & 7) << 4))) = hv;
#pragma unroll
      for (int k = 0; k < 4; ++k) {
        const int d = c + k;
        const int vr = d >> 1;
        const int off = (((d & 1) << 6) + 2 * r) ^
                        (((((d >> 5) & 7) ^ (vr & 7))) << 4);
        *(f16*)((char*)VT2 + vr * 128 + off) = (f16)((&b1[i].x)[k]);
      }
    }
#pragma unroll
    for (int i = 0; i < 4; ++i) {
      const int c = c0 + 16 + i * 4;
      half4v hv = {(f16)b2[i].x, (f16)b2[i].y, (f16)b2[i].z, (f16)b2[i].w};
      *(half4v*)((char*)Bs + r * 512 + ((2 * c) ^ ((r & 7) << 4))) = hv;
#pragma unroll
      for (int k = 0; k < 4; ++k) {
        const int d = c + k;
        const int vr = d >> 1;
        const int off = (((d & 1) << 6) + 2 * r) ^
                        (((((d >> 5) & 7) ^ (vr & 7))) << 4);
        *(f16*)((char*)VT2 + vr * 128 + off) = (f16)((&b2[i].x)[k]);
      }
    }
    __syncthreads();  // LDS ready

    // QK: x = q @ MB^T for this wave's 16t x 32s
    f32x4 xa0 = (f32x4){0.f, 0.f, 0.f, 0.f};
    f32x4 xa1 = (f32x4){0.f, 0.f, 0.f, 0.f};
#pragma unroll
    for (int kf = 0; kf < 8; ++kf) {
      const int rs0 = lc;
      half8 bb0 = *(const half8*)((const char*)Bs + rs0 * 512 +
                                  ((kf * 64 + q * 16) ^ ((rs0 & 7) << 4)));
      xa0 = MFMA16(aq[kf], bb0, xa0);
      const int rs1 = 16 + lc;
      half8 bb1 = *(const half8*)((const char*)Bs + rs1 * 512 +
                                  ((kf * 64 + q * 16) ^ ((rs1 & 7) << 4)));
      xa1 = MFMA16(aq[kf], bb1, xa1);
    }
    // mask -> p -> nt-store global + per-wave Ps
    const bool k0 = mask[(size_t)b * NS + sb + lc] != 0;
    const bool k1 = mask[(size_t)b * NS + sb + 16 + lc] != 0;
    char* psw = PsB + w * 1280;
#pragma unroll
    for (int j = 0; j < 4; ++j) {
      const float p0 = k0 ? __expf(xa0[j] - mrowv[j]) * linvv[j] : 0.f;
      const float p1 = k1 ? __expf(xa1[j] - mrowv[j]) * linvv[j] : 0.f;
      const int t = t0 + w * 16 + q * 4 + j;
      float* ap = alignv + ((size_t)b * NT + t) * NS + sb;
      __builtin_nontemporal_store(p0, ap + lc);
      __builtin_nontemporal_store(p1, ap + 16 + lc);
      char* psrow = psw + (q * 4 + j) * 80;
      *(f16*)(psrow + 2 * lc) = (f16)p0;
      *(f16*)(psrow + 32 + 2 * lc) = (f16)p1;
    }
    // preload next step's batch1 (flies during PV)
    if (st + 1 < nst) {
      const float4* gn = (const float4*)(gsrc + (size_t)(st + 1) * 32 * ND);
#pragma unroll
      for (int i = 0; i < 4; ++i) b1[i] = gn[i];
    }
    // PV: c += P @ V (A from own Ps band; B from VT2)
    const half8 apv = *(const half8*)(psw + lc * 80 + q * 16);
#pragma unroll
    for (int nbd = 0; nbd < 16; ++nbd) {
      const int d = nbd * 16 + lc;
      const int vr = d >> 1;
      const int off = (((d & 1) << 6) + 16 * q) ^
                      (((((d >> 5) & 7) ^ (vr & 7))) << 4);
      half8 bb = *(const half8*)((const char*)VT2 + vr * 128 + off);
      acc[nbd] = MFMA16(apv, bb, acc[nbd]);
    }
  }

  // epilogue: fp16 split-K partial
  f16* pcb = pc + (size_t)kc * ((size_t)NBATCH * NT * ND);
#pragma unroll
  for (int nbd = 0; nbd < 16; ++nbd)
#pragma unroll
    for (int j = 0; j < 4; ++j) {
      const int t = t0 + w * 16 + q * 4 + j;
      const int d = nbd * 16 + lc;
      __builtin_nontemporal_store((f16)acc[nbd][j],
                                  pcb + ((size_t)b * NT + t) * ND + d);
    }
}

// ---------------- K5: c = sum of kcN fp16 split-K partials ----------------
__global__ __launch_bounds__(256) void k_csum(const f16* __restrict__ pc,
                                              float* __restrict__ outc, int kcN) {
  const size_t i8 = ((size_t)blockIdx.x * 256 + threadIdx.x) * 8;
  const size_t STRIDE = (size_t)NBATCH * NT * ND;
  float rs[8];
#pragma unroll
  for (int j = 0; j < 8; ++j) rs[j] = 0.f;
  for (int kc = 0; kc < kcN; ++kc) {
    half8 v = *(const half8*)(pc + (size_t)kc * STRIDE + i8);
#pragma unroll
    for (int j = 0; j < 8; ++j) rs[j] += (float)v[j];
  }
  *(float4*)(outc + i8) = (float4){rs[0], rs[1], rs[2], rs[3]};
  *(float4*)(outc + i8 + 4) = (float4){rs[4], rs[5], rs[6], rs[7]};
}

extern "C" void kernel_launch(void* const* d_in, const int* in_sizes, int n_in,
                              void* d_out, int out_size, void* d_ws, size_t ws_size,
                              hipStream_t stream) {
  const float* mbank = (const float*)d_in[0];
  const float* src   = (const float*)d_in[1];
  const int*   mask  = (const int*)d_in[2];
  const float* W     = (const float*)d_in[3];

  float* out_c = (float*)d_out;
  float* out_align = out_c + (size_t)NBATCH * NT * ND;

  // ws layout:
  //   [0, 4 MB)          q16   : 8192x256 fp16
  //   [4 MB, +512 KB)    pstats: 8192x8x2 f32
  //   [4.5 MB, +32 KB)   sm
  //   [4.5 MB+32K,+32K)  slinv
  //   [5 MB, 5+kcN*4 MB) pc    : kcN x 2M fp16 split-K partials
  char* ws = (char*)d_ws;
  f16* q16      = (f16*)ws;
  float* pstats = (float*)(ws + (4 << 20));
  float* sm     = (float*)(ws + (4 << 20) + (512 << 10));
  float* slinv  = (float*)(ws + (4 << 20) + (544 << 10));
  f16* pc       = (f16*)(ws + (5 << 20));

  const int kcN = (ws_size >= ((size_t)38 << 20)) ? 8 : 4;

  hipLaunchKernelGGL(k_qproj, dim3(128), dim3(256), 0, stream, src, W, q16);
  hipLaunchKernelGGL(k_fstats, dim3(512), dim3(256), 0, stream,
                     mbank, q16, mask, pstats);
  hipLaunchKernelGGL(k_stats, dim3(32), dim3(256), 0, stream, pstats, sm, slinv);
  hipLaunchKernelGGL(k_pv4, dim3(8 * kcN * 16), dim3(256), 0, stream,
                     mbank, q16, mask, sm, slinv, out_align, pc, kcN);
  hipLaunchKernelGGL(k_csum, dim3(1024), dim3(256), 0, stream, pc, out_c, kcN);
}

// Round 8
// 152.686 us; speedup vs baseline: 2.6465x; 2.6465x over previous
//
#include <hip/hip_runtime.h>
#include <cstdint>
#include <cstddef>

// GlobalAttention (Luong 'general'): q = src@W^T ; x = q@MB^T ; softmax(mask) ; c = P@MB
// Outputs: d_out = [ c (8*1024*256) | align_vectors (8*1024*4096) ] fp32.
// Pipeline: k_qproj -> k_logits3 (QK + raw-x store + online stats) -> k_stats
//        -> k_pv (x -> p in place + PV, fp16 split-K) -> k_csum
//
// R8: recombination of the two PROVEN-fast components. k_logits3 is k_fstats
// (reg-A frags, XCD-pinned b=bid&7, ~40us measured) plus R4's coalesced raw-x
// f32 store into the align region. k_pv is R4's measured-fast kernel verbatim
// (in-place x->p, per-thread-owned slabs, strided V staging), grid flattened
// for the XCD batch pin. R5-R7's experimental staging variants all regressed
// and are abandoned.

typedef _Float16 f16;
typedef _Float16 half8 __attribute__((ext_vector_type(8)));
typedef _Float16 half4v __attribute__((ext_vector_type(4)));
typedef float f32x4 __attribute__((ext_vector_type(4)));

#define MFMA16(a, b, c) __builtin_amdgcn_mfma_f32_16x16x32_f16((a), (b), (c), 0, 0, 0)

static constexpr int NBATCH = 8;
static constexpr int NT = 1024;   // TGT
static constexpr int NS = 4096;   // SRC
static constexpr int ND = 256;    // SDIM == TDIM
static constexpr float NEGBIG = -3.0e38f;

__device__ __forceinline__ int swz(int row, int byteInRow) {
  return byteInRow ^ ((row & 7) << 4);
}

// ---------------- K1: q16 = source @ W^T (fp16 out) ----------------
__global__ __launch_bounds__(256) void k_qproj(const float* __restrict__ src,
                                               const float* __restrict__ W,
                                               f16* __restrict__ q16) {
  __shared__ __align__(16) f16 As[64 * 64];
  __shared__ __align__(16) f16 Bs[256 * 64];
  const int tid = threadIdx.x;
  const int w = tid >> 6, l = tid & 63;
  const int wt = w >> 1, wn = w & 1;
  const int q = l >> 4, lc = l & 15;
  const int t0 = blockIdx.x * 64;

  f32x4 acc[2][8];
#pragma unroll
  for (int i = 0; i < 2; ++i)
#pragma unroll
    for (int j = 0; j < 8; ++j) acc[i][j] = (f32x4){0.f, 0.f, 0.f, 0.f};

  for (int k0 = 0; k0 < 256; k0 += 64) {
    __syncthreads();
    {
      const int r = tid >> 2, c2 = (tid & 3) * 2;
      const float* g = src + (size_t)(t0 + r) * 256 + k0 + c2 * 8;
      float4 f0 = ((const float4*)g)[0], f1 = ((const float4*)g)[1];
      float4 f2 = ((const float4*)g)[2], f3 = ((const float4*)g)[3];
      half8 h0 = {(f16)f0.x, (f16)f0.y, (f16)f0.z, (f16)f0.w,
                  (f16)f1.x, (f16)f1.y, (f16)f1.z, (f16)f1.w};
      half8 h1 = {(f16)f2.x, (f16)f2.y, (f16)f2.z, (f16)f2.w,
                  (f16)f3.x, (f16)f3.y, (f16)f3.z, (f16)f3.w};
      *(half8*)((char*)As + r * 128 + swz(r, c2 * 16)) = h0;
      *(half8*)((char*)As + r * 128 + swz(r, c2 * 16 + 16)) = h1;
    }
    {
      const int n = tid;
      const float* g = W + (size_t)n * 256 + k0;
#pragma unroll
      for (int c = 0; c < 8; ++c) {
        float4 f0 = ((const float4*)(g + c * 8))[0];
        float4 f1 = ((const float4*)(g + c * 8))[1];
        half8 h = {(f16)f0.x, (f16)f0.y, (f16)f0.z, (f16)f0.w,
                   (f16)f1.x, (f16)f1.y, (f16)f1.z, (f16)f1.w};
        *(half8*)((char*)Bs + n * 128 + swz(n, c * 16)) = h;
      }
    }
    __syncthreads();
    half8 a[2][2], bb[8][2];
#pragma unroll
    for (int mb = 0; mb < 2; ++mb)
#pragma unroll
      for (int kf = 0; kf < 2; ++kf) {
        const int r = wt * 32 + mb * 16 + lc;
        a[mb][kf] = *(const half8*)((const char*)As + r * 128 + swz(r, kf * 64 + q * 16));
      }
#pragma unroll
    for (int nb = 0; nb < 8; ++nb)
#pragma unroll
      for (int kf = 0; kf < 2; ++kf) {
        const int r = wn * 128 + nb * 16 + lc;
        bb[nb][kf] = *(const half8*)((const char*)Bs + r * 128 + swz(r, kf * 64 + q * 16));
      }
#pragma unroll
    for (int kf = 0; kf < 2; ++kf)
#pragma unroll
      for (int mb = 0; mb < 2; ++mb)
#pragma unroll
        for (int nb = 0; nb < 8; ++nb)
          acc[mb][nb] = MFMA16(a[mb][kf], bb[nb][kf], acc[mb][nb]);
  }
#pragma unroll
  for (int mb = 0; mb < 2; ++mb)
#pragma unroll
    for (int nb = 0; nb < 8; ++nb)
#pragma unroll
      for (int j = 0; j < 4; ++j) {
        const int t = t0 + wt * 32 + mb * 16 + q * 4 + j;
        const int n = wn * 128 + nb * 16 + lc;
        q16[(size_t)t * 256 + n] = (f16)acc[mb][nb][j];
      }
}

// ---------------- K2: QK + raw-x store + online (m, sumexp) partials ----------
// k_fstats geometry (proven ~40us): flat grid 512, b = bid&7 (XCD pin),
// sc = (bid>>3)&7 (512-s chunk), tt = bid>>6 (128-t tile). block 256 = 4 waves,
// each wave owns 32 t-rows; q A-frags in registers; Bs staged per 64-s step.
// Delta vs k_fstats: masked raw x is ALSO stored (f32, coalesced) to align.
__global__ __launch_bounds__(256, 3) void k_logits3(const float* __restrict__ mbank,
                                                    const f16* __restrict__ q16,
                                                    const int* __restrict__ mask,
                                                    float* __restrict__ alignv,
                                                    float* __restrict__ pstats) {
  __shared__ __align__(16) f16 Bs[64 * 256];  // [s][d] f16, 512B rows, swizzled (32 KB)
  const int tid = threadIdx.x;
  const int w = tid >> 6, l = tid & 63;
  const int q = l >> 4, lc = l & 15;
  const int bid = blockIdx.x;
  const int b = bid & 7;
  const int sc = (bid >> 3) & 7;
  const int tt = bid >> 6;
  const int t0 = tt * 128;
  const int s0 = sc * 512;

  half8 aq[2][8];
#pragma unroll
  for (int mb = 0; mb < 2; ++mb)
#pragma unroll
    for (int kf = 0; kf < 8; ++kf)
      aq[mb][kf] = *(const half8*)(q16 +
          (size_t)(b * NT + t0 + w * 32 + mb * 16 + lc) * 256 + kf * 32 + q * 8);

  float mrun[8], lrun[8];
#pragma unroll
  for (int i = 0; i < 8; ++i) { mrun[i] = NEGBIG; lrun[i] = 0.f; }

  const int br = tid >> 2;
  const int cb = (tid & 3) * 64;
  for (int st = 0; st < 8; ++st) {
    const int sb = s0 + st * 64;
    __syncthreads();
    {
      const float4* g = (const float4*)(mbank + ((size_t)b * NS + sb + br) * ND + cb);
#pragma unroll
      for (int i = 0; i < 8; ++i) {
        float4 f0 = g[2 * i], f1 = g[2 * i + 1];
        half8 h = {(f16)f0.x, (f16)f0.y, (f16)f0.z, (f16)f0.w,
                   (f16)f1.x, (f16)f1.y, (f16)f1.z, (f16)f1.w};
        *(half8*)((char*)Bs + br * 512 + swz(br, cb * 2 + i * 16)) = h;
      }
    }
    __syncthreads();
    f32x4 xacc[2][4];
#pragma unroll
    for (int i = 0; i < 2; ++i)
#pragma unroll
      for (int j = 0; j < 4; ++j) xacc[i][j] = (f32x4){0.f, 0.f, 0.f, 0.f};
#pragma unroll
    for (int kf = 0; kf < 8; ++kf)
#pragma unroll
      for (int nb = 0; nb < 4; ++nb) {
        const int rs = nb * 16 + lc;
        half8 bb = *(const half8*)((const char*)Bs + rs * 512 + swz(rs, kf * 64 + q * 16));
#pragma unroll
        for (int mb = 0; mb < 2; ++mb)
          xacc[mb][nb] = MFMA16(aq[mb][kf], bb, xacc[mb][nb]);
      }
    bool keep[4];
#pragma unroll
    for (int nb = 0; nb < 4; ++nb)
      keep[nb] = mask[(size_t)b * NS + sb + nb * 16 + lc] != 0;
#pragma unroll
    for (int mb = 0; mb < 2; ++mb)
#pragma unroll
      for (int j = 0; j < 4; ++j) {
        float v[4];
#pragma unroll
        for (int nb = 0; nb < 4; ++nb) v[nb] = keep[nb] ? xacc[mb][nb][j] : NEGBIG;
        const int tl = w * 32 + mb * 16 + q * 4 + j;
        // raw-x store (R4 pattern): 16-lane groups write 64B segments
        float* ab = alignv + ((size_t)b * NT + t0 + tl) * NS + sb;
#pragma unroll
        for (int nb = 0; nb < 4; ++nb) ab[nb * 16 + lc] = v[nb];
        float m2 = fmaxf(fmaxf(v[0], v[1]), fmaxf(v[2], v[3]));
#pragma unroll
        for (int d = 1; d < 16; d <<= 1) m2 = fmaxf(m2, __shfl_xor(m2, d));
        float s2 = 0.f;
#pragma unroll
        for (int nb = 0; nb < 4; ++nb) s2 += __expf(v[nb] - m2);
#pragma unroll
        for (int d = 1; d < 16; d <<= 1) s2 += __shfl_xor(s2, d);
        const int idx = mb * 4 + j;
        const float mn = fmaxf(mrun[idx], m2);
        lrun[idx] = lrun[idx] * __expf(mrun[idx] - mn) + s2 * __expf(m2 - mn);
        mrun[idx] = mn;
      }
  }
  if (lc == 0) {
#pragma unroll
    for (int mb = 0; mb < 2; ++mb)
#pragma unroll
      for (int j = 0; j < 4; ++j) {
        const int row = t0 + w * 32 + mb * 16 + q * 4 + j;
        const int idx = mb * 4 + j;
        pstats[(((size_t)b * NT + row) * 8 + sc) * 2 + 0] = mrun[idx];
        pstats[(((size_t)b * NT + row) * 8 + sc) * 2 + 1] = lrun[idx];
      }
  }
}

// ---------------- K3: reduce 8 chunk partials -> m, 1/l per row ----------------
__global__ __launch_bounds__(256) void k_stats(const float* __restrict__ pstats,
                                               float* __restrict__ sm,
                                               float* __restrict__ slinv) {
  const int r = blockIdx.x * 256 + threadIdx.x;
  const float4* p = (const float4*)(pstats + (size_t)r * 16);
  float4 v[4];
  float mm = NEGBIG;
#pragma unroll
  for (int i = 0; i < 4; ++i) {
    v[i] = p[i];
    mm = fmaxf(mm, fmaxf(v[i].x, v[i].z));
  }
  float ll = 0.f;
#pragma unroll
  for (int i = 0; i < 4; ++i)
    ll += v[i].y * __expf(v[i].x - mm) + v[i].w * __expf(v[i].z - mm);
  sm[r] = mm;
  slinv[r] = (ll > 0.f) ? (1.f / ll) : 0.f;
}

// ---------------- K4: p = exp(x-m)/l (once per element, in place) ; partial c = P@V ----
// R4's measured-fast kernel, verbatim except flat grid with b = bid&7 XCD pin.
// flat grid 512: b = bid&7, kc = (bid>>3)&3 (1024-s chunk), tt = bid>>5 (64-t).
// block 512 (8 waves: 2 t-groups x 4 d-groups); 16 steps of 64 s.
__global__ __launch_bounds__(512, 4) void k_pv(const float* __restrict__ mbank,
                                               const float* __restrict__ sm,
                                               const float* __restrict__ slinv,
                                               float* __restrict__ alignv,
                                               f16* __restrict__ pc) {
  __shared__ __align__(16) f16 VT[256 * 64];  // [d][s] transposed, swizzled (32 KB)
  __shared__ __align__(16) f16 Ps[64 * 64];   // [t][s] p-tile fp16, swizzled (8 KB)
  const int tid = threadIdx.x;
  const int w = tid >> 6, l = tid & 63;
  const int wtg = w >> 2, wd = w & 3;
  const int q = l >> 4, lc = l & 15;
  const int bid = blockIdx.x;
  const int b = bid & 7;
  const int kc = (bid >> 3) & 3;
  const int tt = bid >> 5;
  const int t0 = tt * 64;
  const int s0 = kc * 1024;

  const int pt = tid >> 3;
  const int ps8 = (tid & 7) * 8;
  const float mv = sm[(size_t)b * NT + t0 + pt];
  const float lv = slinv[(size_t)b * NT + t0 + pt];
  float* xrow = alignv + ((size_t)b * NT + t0 + pt) * NS + s0 + ps8;

  f32x4 acc[2][4];
#pragma unroll
  for (int i = 0; i < 2; ++i)
#pragma unroll
    for (int j = 0; j < 4; ++j) acc[i][j] = (f32x4){0.f, 0.f, 0.f, 0.f};

  const int dstage = (w & 3) * 64 + l;
  const int shalf = (w >> 2) * 32;

  float4 xA = ((const float4*)xrow)[0];
  float4 xB = ((const float4*)xrow)[1];

  for (int st = 0; st < 16; ++st) {
    const int sb = s0 + st * 64;
    __syncthreads();
    {
#pragma unroll
      for (int i = 0; i < 8; ++i) {
        const int s4 = shalf + i * 4;
        const float* g = mbank + ((size_t)b * NS + sb + s4) * ND + dstage;
        const float f0 = g[0], f1 = g[ND], f2 = g[2 * ND], f3 = g[3 * ND];
        half4v h = {(f16)f0, (f16)f1, (f16)f2, (f16)f3};
        *(half4v*)((char*)VT + dstage * 128 + swz(dstage, s4 * 2)) = h;
      }
    }
    {
      const float p0 = __expf(xA.x - mv) * lv, p1 = __expf(xA.y - mv) * lv;
      const float p2 = __expf(xA.z - mv) * lv, p3 = __expf(xA.w - mv) * lv;
      const float p4 = __expf(xB.x - mv) * lv, p5 = __expf(xB.y - mv) * lv;
      const float p6 = __expf(xB.z - mv) * lv, p7 = __expf(xB.w - mv) * lv;
      float* xp = xrow + st * 64;
      ((float4*)xp)[0] = (float4){p0, p1, p2, p3};
      ((float4*)xp)[1] = (float4){p4, p5, p6, p7};
      half8 h = {(f16)p0, (f16)p1, (f16)p2, (f16)p3,
                 (f16)p4, (f16)p5, (f16)p6, (f16)p7};
      *(half8*)((char*)Ps + pt * 128 + swz(pt, ps8 * 2)) = h;
    }
    if (st < 15) {
      const float* xn = xrow + (st + 1) * 64;
      xA = ((const float4*)xn)[0];
      xB = ((const float4*)xn)[1];
    }
    __syncthreads();
    half8 a[2][2];
#pragma unroll
    for (int mb = 0; mb < 2; ++mb)
#pragma unroll
      for (int kf = 0; kf < 2; ++kf) {
        const int r = wtg * 32 + mb * 16 + lc;
        a[mb][kf] = *(const half8*)((const char*)Ps + r * 128 + swz(r, kf * 64 + q * 16));
      }
#pragma unroll
    for (int kf = 0; kf < 2; ++kf)
#pragma unroll
      for (int nb = 0; nb < 4; ++nb) {
        const int d = wd * 64 + nb * 16 + lc;
        half8 bbt = *(const half8*)((const char*)VT + d * 128 + swz(d, kf * 64 + q * 16));
#pragma unroll
        for (int mb = 0; mb < 2; ++mb)
          acc[mb][nb] = MFMA16(a[mb][kf], bbt, acc[mb][nb]);
      }
  }

#pragma unroll
  for (int mb = 0; mb < 2; ++mb)
#pragma unroll
    for (int nb = 0; nb < 4; ++nb)
#pragma unroll
      for (int j = 0; j < 4; ++j) {
        const int t = t0 + wtg * 32 + mb * 16 + q * 4 + j;
        const int d = wd * 64 + nb * 16 + lc;
        pc[(size_t)kc * ((size_t)NBATCH * NT * ND) + ((size_t)b * NT + t) * ND + d] =
            (f16)acc[mb][nb][j];
      }
}

// ---------------- K5: c = sum of 4 fp16 split-K partials ----------------
__global__ __launch_bounds__(256) void k_csum(const f16* __restrict__ pc,
                                              float* __restrict__ outc) {
  const size_t i8 = ((size_t)blockIdx.x * 256 + threadIdx.x) * 8;
  const size_t STRIDE = (size_t)NBATCH * NT * ND;
  half8 a = *(const half8*)(pc + i8);
  half8 b = *(const half8*)(pc + STRIDE + i8);
  half8 c = *(const half8*)(pc + 2 * STRIDE + i8);
  half8 d = *(const half8*)(pc + 3 * STRIDE + i8);
  float4 r0, r1;
  r0.x = (float)a[0] + (float)b[0] + (float)c[0] + (float)d[0];
  r0.y = (float)a[1] + (float)b[1] + (float)c[1] + (float)d[1];
  r0.z = (float)a[2] + (float)b[2] + (float)c[2] + (float)d[2];
  r0.w = (float)a[3] + (float)b[3] + (float)c[3] + (float)d[3];
  r1.x = (float)a[4] + (float)b[4] + (float)c[4] + (float)d[4];
  r1.y = (float)a[5] + (float)b[5] + (float)c[5] + (float)d[5];
  r1.z = (float)a[6] + (float)b[6] + (float)c[6] + (float)d[6];
  r1.w = (float)a[7] + (float)b[7] + (float)c[7] + (float)d[7];
  *(float4*)(outc + i8) = r0;
  *(float4*)(outc + i8 + 4) = r1;
}

extern "C" void kernel_launch(void* const* d_in, const int* in_sizes, int n_in,
                              void* d_out, int out_size, void* d_ws, size_t ws_size,
                              hipStream_t stream) {
  const float* mbank = (const float*)d_in[0];  // (8,4096,256) f32
  const float* src   = (const float*)d_in[1];  // (8,1024,256) f32
  const int*   mask  = (const int*)d_in[2];    // (8,4096) bool->int
  const float* W     = (const float*)d_in[3];  // (256,256) f32

  float* out_c = (float*)d_out;
  float* out_align = out_c + (size_t)NBATCH * NT * ND;

  // ws layout (24 MB total):
  //   [0, 4 MB)          q16   : 8192x256 fp16
  //   [4 MB, +512 KB)    pstats: 8192x8x2 f32
  //   [4.5 MB, +32 KB)   sm
  //   [4.5 MB+32K,+32K)  slinv
  //   [8 MB, 24 MB)      pc    : 4 x 2M fp16 split-K partials
  char* ws = (char*)d_ws;
  f16* q16      = (f16*)ws;
  float* pstats = (float*)(ws + (4 << 20));
  float* sm     = (float*)(ws + (4 << 20) + (512 << 10));
  float* slinv  = (float*)(ws + (4 << 20) + (544 << 10));
  f16* pc       = (f16*)(ws + (8 << 20));

  hipLaunchKernelGGL(k_qproj, dim3(128), dim3(256), 0, stream, src, W, q16);
  hipLaunchKernelGGL(k_logits3, dim3(512), dim3(256), 0, stream,
                     mbank, q16, mask, out_align, pstats);
  hipLaunchKernelGGL(k_stats, dim3(32), dim3(256), 0, stream, pstats, sm, slinv);
  hipLaunchKernelGGL(k_pv, dim3(512), dim3(512), 0, stream,
                     mbank, sm, slinv, out_align, pc);
  hipLaunchKernelGGL(k_csum, dim3(1024), dim3(256), 0, stream, pc, out_c);
}